// Round 2
// baseline (907.268 us; speedup 1.0000x reference)
//
#include <hip/hip_runtime.h>
#include <stdint.h>

#define D_DIM 256
#define N_EMB 8192
#define M_TOT 16384
#define TMB 128  // rows per block (4 waves x 32 rows)
#define TN 64
#define QK_SCALE 0.0625f
#define DELTA 4e-3f
#define LN_EPS 1e-5f

typedef _Float16 f16;
typedef f16 f16x8 __attribute__((ext_vector_type(8)));
typedef f16 f16x4 __attribute__((ext_vector_type(4)));
typedef float f32x4 __attribute__((ext_vector_type(4)));

// ws layout:
// [0,4MB) embd_h [8192][256] f16 ; [4MB,8MB) embd_th [256][8192] f16
// [8MB,+4) count ; [8MB+64,+64KB) list ; [8MB+128KB,+1MB) part_stats
// [10MB, 10MB+S*16MB) part_acc
#define WS_EMBD_H 0ul
#define WS_EMBD_TH (4ul << 20)
#define WS_COUNT (8ul << 20)
#define WS_LIST ((8ul << 20) + 64ul)
#define WS_STATS ((8ul << 20) + (128ul << 10))
#define WS_PACC (10ul << 20)
#define PACC_ONE 16777216ul  // 16384*256*4 bytes
#define PACC_ELEMS 4194304ul // 16384*256

// ---------------- prep: fp32 embd -> f16 in both layouts ----------------
__global__ __launch_bounds__(256) void prep_kernel(const float* __restrict__ embd,
                                                   f16* __restrict__ embd_h,
                                                   f16* __restrict__ embd_th,
                                                   unsigned* __restrict__ count) {
  if (blockIdx.x == 0 && threadIdx.x == 0) *count = 0u;
  __shared__ f16 tile[64][72];
  const int t = threadIdx.x;
  const int nb = (blockIdx.x >> 2) * 64;
  const int db = (blockIdx.x & 3) * 64;
  const int nl = t >> 2;
  const int dl = (t & 3) * 16;
  const float4* src = (const float4*)(embd + (size_t)(nb + nl) * 256 + db + dl);
  f16 vals[16];
#pragma unroll
  for (int q = 0; q < 4; ++q) {
    float4 v = src[q];
    vals[q * 4 + 0] = (f16)v.x;
    vals[q * 4 + 1] = (f16)v.y;
    vals[q * 4 + 2] = (f16)v.z;
    vals[q * 4 + 3] = (f16)v.w;
  }
  f16* dst = embd_h + (size_t)(nb + nl) * 256 + db + dl;
#pragma unroll
  for (int q = 0; q < 2; ++q) {
    f16x8 pack;
#pragma unroll
    for (int j = 0; j < 8; ++j) pack[j] = vals[q * 8 + j];
    *(f16x8*)(dst + q * 8) = pack;
  }
#pragma unroll
  for (int j = 0; j < 16; ++j) tile[nl][dl + j] = vals[j];
  __syncthreads();
  const int dl2 = t >> 2;
  const int nbase = (t & 3) * 16;
  f16* dstT = embd_th + (size_t)(db + dl2) * 8192 + nb + nbase;
#pragma unroll
  for (int q = 0; q < 2; ++q) {
    f16x8 pack;
#pragma unroll
    for (int j = 0; j < 8; ++j) pack[j] = tile[nbase + q * 8 + j][dl2];
    *(f16x8*)(dstT + q * 8) = pack;
  }
}

// ---------------- fused: LN + flash softmax-quantize, 32 rows/wave ----------------
// LDS: [0,32768) x-tile(phase1)/embd_nd [64n][256d] swz
//      [32768,40960) embd_dn quarter [64d][64n] swz
//      [40960,57344) P: wave w at +w*4096, [32r][64n] f16 swz
__global__ __launch_bounds__(256, 2) void fused_kernel(
    const float* __restrict__ input, const float* __restrict__ ln_w,
    const float* __restrict__ ln_b, const f16* __restrict__ embd_h,
    const f16* __restrict__ embd_th, float* __restrict__ out_q,
    float* __restrict__ out_idx, unsigned* __restrict__ count,
    int* __restrict__ list, float* __restrict__ part_acc,
    float* __restrict__ part_stats, int S, int slog2, int nchunks, int direct) {
  __shared__ __align__(16) char lds[57344];
  const int tid = threadIdx.x;
  const int lane = tid & 63;
  const int w = tid >> 6;
  const int cl = lane & 15;
  const int g = lane >> 4;
  const int bid = blockIdx.x;
  const int s = bid & (S - 1);
  const int mb = bid >> slog2;
  const int R0 = mb * TMB;
  const int nb0 = s * (N_EMB >> slog2);

  f16x8 Q[2][8];

  // ---- Phase 1: LayerNorm 128 rows in two 64-row halves ----
#pragma unroll
  for (int h = 0; h < 2; ++h) {
    {
      const int rl = tid >> 2;  // 0..63 row within half
      const int seg = tid & 3;
      const float* rowp = input + (size_t)(R0 + h * 64 + rl) * 256 + seg * 64;
      float sm = 0.f, ssq = 0.f;
#pragma unroll
      for (int q = 0; q < 16; ++q) {
        float4 x4 = ((const float4*)rowp)[q];
        sm += x4.x + x4.y + x4.z + x4.w;
        ssq += x4.x * x4.x + x4.y * x4.y + x4.z * x4.z + x4.w * x4.w;
      }
      sm += __shfl_xor(sm, 1);
      sm += __shfl_xor(sm, 2);
      ssq += __shfl_xor(ssq, 1);
      ssq += __shfl_xor(ssq, 2);
      const float mean = sm * (1.f / 256.f);
      const float var = ssq * (1.f / 256.f) - mean * mean;
      const float rstd = 1.0f / sqrtf(var + LN_EPS);
#pragma unroll
      for (int q = 0; q < 16; ++q) {
        float4 x4 = ((const float4*)rowp)[q];
        float4 w4 = ((const float4*)(ln_w + seg * 64))[q];
        float4 b4 = ((const float4*)(ln_b + seg * 64))[q];
        f16x4 hv;
        hv[0] = (f16)((x4.x - mean) * rstd * w4.x + b4.x);
        hv[1] = (f16)((x4.y - mean) * rstd * w4.y + b4.y);
        hv[2] = (f16)((x4.z - mean) * rstd * w4.z + b4.z);
        hv[3] = (f16)((x4.w - mean) * rstd * w4.w + b4.w);
        const int d = seg * 64 + q * 4;
        const int byte = (rl * 512 + d * 2) ^ ((rl & 7) << 4);
        *(f16x4*)(lds + byte) = hv;
      }
    }
    __syncthreads();
    if ((w >> 1) == h) {
      const int wl = w & 1;
#pragma unroll
      for (int rf = 0; rf < 2; ++rf) {
        const int rt = wl * 32 + rf * 16 + cl;
#pragma unroll
        for (int kc = 0; kc < 8; ++kc)
          Q[rf][kc] =
              *(const f16x8*)(lds + rt * 512 + (((kc * 4 + g) ^ (rt & 7)) << 4));
      }
    }
    __syncthreads();
  }

  f32x4 acc[2][16] = {};
  float m_run[2][4], l_run[2][4], m2_run[2][4], alpha[2][4];
  int i1_run[2][4];
#pragma unroll
  for (int rf = 0; rf < 2; ++rf)
#pragma unroll
    for (int i = 0; i < 4; ++i) {
      m_run[rf][i] = -__builtin_inff();
      m2_run[rf][i] = -__builtin_inff();
      l_run[rf][i] = 0.f;
      i1_run[rf][i] = 0;
    }

  char* const Pb = lds + 40960 + w * 4096;

  for (int c = 0; c < nchunks; ++c) {
    const int nb = nb0 + c * TN;
    __syncthreads();  // prior chunk's LDS reads done
    // stage embd_nd [64][256]
    {
      const f16x8* srcN = (const f16x8*)(embd_h + (size_t)nb * 256);
#pragma unroll
      for (int i = 0; i < 8; ++i) {
        const int u = i * 256 + tid;
        const int n = u >> 5, un = u & 31;
        f16x8 val = srcN[u];
        *(f16x8*)(lds + n * 512 + ((un ^ (n & 7)) << 4)) = val;
      }
      // stage dn quarter 0 (d rows 0..63 of this chunk's V^T)
      const char* srcT = (const char*)embd_th + (size_t)nb * 2;
#pragma unroll
      for (int i = 0; i < 2; ++i) {
        const int u = i * 256 + tid;
        const int dl = u >> 3, j = u & 7;
        f16x8 val = *(const f16x8*)(srcT + (size_t)dl * 16384 + j * 16);
        *(f16x8*)(lds + 32768 + dl * 128 + ((j ^ (dl & 7)) << 4)) = val;
      }
    }
    __syncthreads();

    // ---- QK^T ----
    f32x4 Sf[2][4] = {};
#pragma unroll
    for (int kc = 0; kc < 8; ++kc) {
      f16x8 b[4];
#pragma unroll
      for (int fn = 0; fn < 4; ++fn) {
        const int n = fn * 16 + cl;
        b[fn] = *(const f16x8*)(lds + n * 512 + (((kc * 4 + g) ^ (n & 7)) << 4));
      }
#pragma unroll
      for (int rf = 0; rf < 2; ++rf)
#pragma unroll
        for (int fn = 0; fn < 4; ++fn)
          Sf[rf][fn] =
              __builtin_amdgcn_mfma_f32_16x16x32_f16(Q[rf][kc], b[fn], Sf[rf][fn], 0, 0, 0);
    }

    // ---- online softmax + top-2, P write (per rowfrag) ----
    int grow = 0;
#pragma unroll
    for (int rf = 0; rf < 2; ++rf) {
      float sv[4][4];
#pragma unroll
      for (int fn = 0; fn < 4; ++fn)
#pragma unroll
        for (int i = 0; i < 4; ++i) sv[i][fn] = Sf[rf][fn][i] * QK_SCALE;
#pragma unroll
      for (int i = 0; i < 4; ++i) {
        const float a0 = sv[i][0], a1 = sv[i][1], a2 = sv[i][2], a3 = sv[i][3];
        const int j0 = nb + cl, j1 = nb + 16 + cl, j2 = nb + 32 + cl,
                  j3 = nb + 48 + cl;
        float hi1, lo1, hi2, lo2;
        int ii1, ii2;
        if (a1 > a0) { hi1 = a1; ii1 = j1; lo1 = a0; }
        else { hi1 = a0; ii1 = j0; lo1 = a1; }
        if (a3 > a2) { hi2 = a3; ii2 = j3; lo2 = a2; }
        else { hi2 = a2; ii2 = j2; lo2 = a3; }
        float t1, t2;
        int ti;
        if (hi2 > hi1) { t1 = hi2; ti = ii2; t2 = fmaxf(lo2, hi1); }
        else { t1 = hi1; ti = ii1; t2 = fmaxf(lo1, hi2); }
#pragma unroll
        for (int mk = 1; mk <= 8; mk <<= 1) {
          const float ov1 = __shfl_xor(t1, mk);
          const int oi = __shfl_xor(ti, mk);
          const float ov2 = __shfl_xor(t2, mk);
          if (ov1 > t1) { t2 = fmaxf(t1, ov2); t1 = ov1; ti = oi; }
          else { t2 = fmaxf(t2, ov1); }
        }
        const float mold = m_run[rf][i];
        if (t1 > mold) { m2_run[rf][i] = fmaxf(mold, t2); i1_run[rf][i] = ti; grow = 1; }
        else { m2_run[rf][i] = fmaxf(m2_run[rf][i], t1); }
        const float mnew = fmaxf(mold, t1);
        alpha[rf][i] = __expf(mold - mnew);
        m_run[rf][i] = mnew;
      }
#pragma unroll
      for (int i = 0; i < 4; ++i) {
        float rsum = 0.f;
#pragma unroll
        for (int fn = 0; fn < 4; ++fn) {
          const float p = __expf(sv[i][fn] - m_run[rf][i]);
          sv[i][fn] = p;
          rsum += p;
        }
        rsum += __shfl_xor(rsum, 1);
        rsum += __shfl_xor(rsum, 2);
        rsum += __shfl_xor(rsum, 4);
        rsum += __shfl_xor(rsum, 8);
        l_run[rf][i] = l_run[rf][i] * alpha[rf][i] + rsum;
      }
      // P write: conflict-free key (r>>1)&7
#pragma unroll
      for (int i = 0; i < 4; ++i) {
        const int r = rf * 16 + g * 4 + i;
        const int kr = (r >> 1) & 7;
#pragma unroll
        for (int fn = 0; fn < 4; ++fn) {
          const int col = fn * 16 + cl;
          const int off = r * 128 + (((col >> 3) ^ kr) << 4) + ((col & 7) << 1);
          *(f16*)(Pb + off) = (f16)sv[i][fn];
        }
      }
    }
    if (__any(grow)) {
#pragma unroll
      for (int rf = 0; rf < 2; ++rf)
#pragma unroll
        for (int f = 0; f < 16; ++f) {
          acc[rf][f][0] *= alpha[rf][0];
          acc[rf][f][1] *= alpha[rf][1];
          acc[rf][f][2] *= alpha[rf][2];
          acc[rf][f][3] *= alpha[rf][3];
        }
    }
    // ---- pa fragments ----
    f16x8 pa[2][2];
#pragma unroll
    for (int rf = 0; rf < 2; ++rf)
#pragma unroll
      for (int k2 = 0; k2 < 2; ++k2) {
        const int row = rf * 16 + cl;
        pa[rf][k2] = *(const f16x8*)(
            Pb + row * 128 + (((k2 * 4 + g) ^ ((row >> 1) & 7)) << 4));
      }
    // ---- PV quarter 0 ----
#pragma unroll
    for (int fl = 0; fl < 4; ++fl) {
      const int dl = fl * 16 + cl;
#pragma unroll
      for (int k2 = 0; k2 < 2; ++k2) {
        f16x8 vb = *(const f16x8*)(lds + 32768 + dl * 128 +
                                   (((k2 * 4 + g) ^ (dl & 7)) << 4));
        acc[0][fl] = __builtin_amdgcn_mfma_f32_16x16x32_f16(pa[0][k2], vb, acc[0][fl], 0, 0, 0);
        acc[1][fl] = __builtin_amdgcn_mfma_f32_16x16x32_f16(pa[1][k2], vb, acc[1][fl], 0, 0, 0);
      }
    }
    // ---- PV quarters 1..3 with restage ----
#pragma unroll
    for (int qd = 1; qd < 4; ++qd) {
      __syncthreads();
      {
        const char* srcT = (const char*)embd_th + (size_t)nb * 2;
#pragma unroll
        for (int i = 0; i < 2; ++i) {
          const int u = i * 256 + tid;
          const int dl = u >> 3, j = u & 7;
          f16x8 val = *(const f16x8*)(srcT + (size_t)(qd * 64 + dl) * 16384 + j * 16);
          *(f16x8*)(lds + 32768 + dl * 128 + ((j ^ (dl & 7)) << 4)) = val;
        }
      }
      __syncthreads();
#pragma unroll
      for (int fl = 0; fl < 4; ++fl) {
        const int f = qd * 4 + fl;
        const int dl = fl * 16 + cl;
#pragma unroll
        for (int k2 = 0; k2 < 2; ++k2) {
          f16x8 vb = *(const f16x8*)(lds + 32768 + dl * 128 +
                                     (((k2 * 4 + g) ^ (dl & 7)) << 4));
          acc[0][f] = __builtin_amdgcn_mfma_f32_16x16x32_f16(pa[0][k2], vb, acc[0][f], 0, 0, 0);
          acc[1][f] = __builtin_amdgcn_mfma_f32_16x16x32_f16(pa[1][k2], vb, acc[1][f], 0, 0, 0);
        }
      }
    }
  }

  // ---- epilogue ----
  if (direct) {
#pragma unroll
    for (int rf = 0; rf < 2; ++rf) {
      float invl[4];
#pragma unroll
      for (int i = 0; i < 4; ++i) invl[i] = 1.0f / l_run[rf][i];
#pragma unroll
      for (int f = 0; f < 16; ++f)
#pragma unroll
        for (int i = 0; i < 4; ++i) {
          const int r = R0 + w * 32 + rf * 16 + g * 4 + i;
          out_q[(size_t)r * 256 + f * 16 + cl] = acc[rf][f][i] * invl[i];
        }
    }
    if (cl == 0) {
#pragma unroll
      for (int rf = 0; rf < 2; ++rf)
#pragma unroll
        for (int i = 0; i < 4; ++i) {
          const int r = R0 + w * 32 + rf * 16 + g * 4 + i;
          out_idx[r] = (float)i1_run[rf][i];
          if (m_run[rf][i] - m2_run[rf][i] <= DELTA) {
            const unsigned pos = atomicAdd(count, 1u);
            list[pos] = r;
          }
        }
    }
  } else {
    float* pout = part_acc + (size_t)s * PACC_ELEMS;
#pragma unroll
    for (int rf = 0; rf < 2; ++rf)
#pragma unroll
      for (int f = 0; f < 16; ++f)
#pragma unroll
        for (int i = 0; i < 4; ++i) {
          const int r = R0 + w * 32 + rf * 16 + g * 4 + i;
          pout[(size_t)r * 256 + f * 16 + cl] = acc[rf][f][i];
        }
    if (cl == 0) {
#pragma unroll
      for (int rf = 0; rf < 2; ++rf)
#pragma unroll
        for (int i = 0; i < 4; ++i) {
          const int r = R0 + w * 32 + rf * 16 + g * 4 + i;
          float4 st;
          st.x = m_run[rf][i];
          st.y = l_run[rf][i];
          st.z = m2_run[rf][i];
          st.w = (float)i1_run[rf][i];
          ((float4*)part_stats)[(size_t)s * M_TOT + r] = st;
        }
    }
  }
}

// ---------------- merge: combine S partials ----------------
__global__ __launch_bounds__(256) void merge_kernel(
    const float* __restrict__ part_acc, const float* __restrict__ part_stats,
    float* __restrict__ out_q, float* __restrict__ out_idx,
    unsigned* __restrict__ count, int* __restrict__ list, int S) {
  const int tid = threadIdx.x;
  const int row = blockIdx.x * 64 + (tid >> 2);
  const int dq = (tid & 3) * 64;
  float m[4], l[4], m2[4], i1[4];
  float mstar = -__builtin_inff();
  for (int s = 0; s < S; ++s) {
    float4 st = ((const float4*)part_stats)[(size_t)s * M_TOT + row];
    m[s] = st.x;
    l[s] = st.y;
    m2[s] = st.z;
    i1[s] = st.w;
    mstar = fmaxf(mstar, st.x);
  }
  float al[4], lstar = 0.f;
  for (int s = 0; s < S; ++s) {
    al[s] = __expf(m[s] - mstar);
    lstar += l[s] * al[s];
  }
  const float inv = 1.0f / lstar;
  for (int q = 0; q < 16; ++q) {
    const size_t off = (size_t)row * 256 + dq + q * 4;
    float ax = 0.f, ay = 0.f, az = 0.f, aw = 0.f;
    for (int s = 0; s < S; ++s) {
      float4 v = *(const float4*)(part_acc + (size_t)s * PACC_ELEMS + off);
      ax += v.x * al[s];
      ay += v.y * al[s];
      az += v.z * al[s];
      aw += v.w * al[s];
    }
    float4 o;
    o.x = ax * inv;
    o.y = ay * inv;
    o.z = az * inv;
    o.w = aw * inv;
    *(float4*)(out_q + off) = o;
  }
  if ((tid & 3) == 0) {
    int sw = 0;
    for (int s = 1; s < S; ++s)
      if (m[s] > m[sw]) sw = s;
    float top2 = m2[sw];
    for (int s = 0; s < S; ++s)
      if (s != sw) top2 = fmaxf(top2, m[s]);
    out_idx[row] = i1[sw];
    if (m[sw] - top2 <= DELTA) {
      const unsigned pos = atomicAdd(count, 1u);
      list[pos] = row;
    }
  }
}

// ---------------- refine: exact fp32 argmax for flagged rows ----------------
__global__ __launch_bounds__(256) void refine_kernel(
    const float* __restrict__ input, const float* __restrict__ ln_w,
    const float* __restrict__ ln_b, const float* __restrict__ embd,
    float* __restrict__ out_idx, const unsigned* __restrict__ count,
    const int* __restrict__ list) {
  __shared__ float xr[2][256];
  __shared__ float redv[256];
  __shared__ int redi[256];
  __shared__ float stat[8];
  const int tid = threadIdx.x;
  const unsigned cnt = *count;
  for (unsigned t = blockIdx.x; t * 2u < cnt; t += gridDim.x) {
    const unsigned rem = cnt - t * 2u;
    const int nrows = rem >= 2u ? 2 : 1;
    for (int rr = 0; rr < 2; ++rr) {
      const int row = list[t * 2u + (unsigned)(rr < nrows ? rr : 0)];
      const float v = input[(size_t)row * 256 + tid];
      float s = v, ss = v * v;
#pragma unroll
      for (int mk = 1; mk <= 32; mk <<= 1) {
        s += __shfl_xor(s, mk);
        ss += __shfl_xor(ss, mk);
      }
      if ((tid & 63) == 0) {
        stat[tid >> 6] = s;
        stat[4 + (tid >> 6)] = ss;
      }
      __syncthreads();
      const float S_ = stat[0] + stat[1] + stat[2] + stat[3];
      const float SS = stat[4] + stat[5] + stat[6] + stat[7];
      const float mean = S_ * (1.f / 256.f);
      const float var = SS * (1.f / 256.f) - mean * mean;
      const float rstd = 1.0f / sqrtf(var + LN_EPS);
      xr[rr][tid] = (v - mean) * rstd * ln_w[tid] + ln_b[tid];
      __syncthreads();
    }
    float b0 = -__builtin_inff(), b1 = -__builtin_inff();
    int i0 = 0, i1_ = 0;
    for (int n = tid; n < 8192; n += 256) {
      const float4* e4 = (const float4*)(embd + (size_t)n * 256);
      float d0 = 0.f, d1 = 0.f;
#pragma unroll 8
      for (int q = 0; q < 64; ++q) {
        const float4 e = e4[q];
        const float4 x0 = *(const float4*)&xr[0][q * 4];
        const float4 x1 = *(const float4*)&xr[1][q * 4];
        d0 += x0.x * e.x + x0.y * e.y + x0.z * e.z + x0.w * e.w;
        d1 += x1.x * e.x + x1.y * e.y + x1.z * e.z + x1.w * e.w;
      }
      if (d0 > b0) { b0 = d0; i0 = n; }
      if (d1 > b1) { b1 = d1; i1_ = n; }
    }
    for (int rr = 0; rr < nrows; ++rr) {
      __syncthreads();
      redv[tid] = rr ? b1 : b0;
      redi[tid] = rr ? i1_ : i0;
      __syncthreads();
      for (int off = 128; off > 0; off >>= 1) {
        if (tid < off) {
          const float ov = redv[tid + off];
          const int oi = redi[tid + off];
          if (ov > redv[tid] || (ov == redv[tid] && oi < redi[tid])) {
            redv[tid] = ov;
            redi[tid] = oi;
          }
        }
        __syncthreads();
      }
      if (tid == 0) out_idx[list[t * 2u + rr]] = (float)redi[0];
    }
  }
}

extern "C" void kernel_launch(void* const* d_in, const int* in_sizes, int n_in,
                              void* d_out, int out_size, void* d_ws,
                              size_t ws_size, hipStream_t stream) {
  (void)in_sizes;
  (void)n_in;
  (void)out_size;
  const float* input = (const float*)d_in[0];
  const float* ln_w = (const float*)d_in[1];
  const float* ln_b = (const float*)d_in[2];
  const float* embd = (const float*)d_in[3];
  float* out_q = (float*)d_out;
  float* out_idx = out_q + (size_t)M_TOT * D_DIM;
  char* ws = (char*)d_ws;
  f16* embd_h = (f16*)(ws + WS_EMBD_H);
  f16* embd_th = (f16*)(ws + WS_EMBD_TH);
  unsigned* count = (unsigned*)(ws + WS_COUNT);
  int* list = (int*)(ws + WS_LIST);
  float* part_stats = (float*)(ws + WS_STATS);
  float* part_acc = (float*)(ws + WS_PACC);

  int S, slog2;
  if (ws_size >= WS_PACC + 4ul * PACC_ONE) {
    S = 4;
    slog2 = 2;
  } else if (ws_size >= WS_PACC + 2ul * PACC_ONE) {
    S = 2;
    slog2 = 1;
  } else {
    S = 1;
    slog2 = 0;
  }
  const int nchunks = (N_EMB / TN) >> slog2;
  const int direct = (S == 1) ? 1 : 0;

  prep_kernel<<<512, 256, 0, stream>>>(embd, embd_h, embd_th, count);
  fused_kernel<<<(M_TOT / TMB) * S, 256, 0, stream>>>(
      input, ln_w, ln_b, embd_h, embd_th, out_q, out_idx, count, list,
      part_acc, part_stats, S, slog2, nchunks, direct);
  if (S > 1)
    merge_kernel<<<M_TOT / 64, 256, 0, stream>>>(part_acc, part_stats, out_q,
                                                 out_idx, count, list, S);
  refine_kernel<<<128, 256, 0, stream>>>(input, ln_w, ln_b, embd, out_idx,
                                         count, list);
}